// Round 1
// baseline (262.911 us; speedup 1.0000x reference)
//
#include <hip/hip_runtime.h>
#include <stdint.h>

typedef __bf16 bf16x8 __attribute__((ext_vector_type(8)));
typedef float  f32x4  __attribute__((ext_vector_type(4)));

#define E_DIM 1024
#define H_DIM 64
#define T_SEQ 4096
#define B_BAT 4
#define M_TOT (B_BAT * T_SEQ)   // 16384

__device__ __forceinline__ uint32_t f2bf1(float f) {
    // round-to-nearest-even fp32 -> bf16 bits (inputs are finite)
    uint32_t u = __float_as_uint(f);
    return (u + 0x7FFFu + ((u >> 16) & 1u)) >> 16;
}
__device__ __forceinline__ uint32_t f2bf2(float lo, float hi) {
    return f2bf1(lo) | (f2bf1(hi) << 16);
}

// ---------------- kernel 0: W fp32 -> bf16 (concatenated [192][1024]) -------
__global__ __launch_bounds__(256) void wcvt(const float* __restrict__ Wq,
                                            const float* __restrict__ Wk,
                                            const float* __restrict__ Wv,
                                            ushort* __restrict__ Wb) {
    int e = (blockIdx.x * 256 + threadIdx.x) * 8;  // grid 96 -> 196608 elems
    const float* src = (e < 65536) ? (Wq + e)
                     : (e < 131072) ? (Wk + (e - 65536))
                     : (Wv + (e - 131072));
    float4 a = *(const float4*)src;
    float4 b = *(const float4*)(src + 4);
    uint4 o;
    o.x = f2bf2(a.x, a.y); o.y = f2bf2(a.z, a.w);
    o.z = f2bf2(b.x, b.y); o.w = f2bf2(b.z, b.w);
    *(uint4*)(Wb + e) = o;
}

// ---------------- kernel 1: QKV projection (bf16 MFMA) ----------------------
// out: qb,kb row-major [16384][64] bf16 ; vtb transposed [B][64][T] bf16
__global__ __launch_bounds__(256) void qkv(const float* __restrict__ x,
                                           const ushort* __restrict__ Wb,
                                           ushort* __restrict__ qb,
                                           ushort* __restrict__ kb,
                                           ushort* __restrict__ vtb) {
    __shared__ ushort wlds[2][192 * 32];  // 12 KB per buffer
    const int tid = threadIdx.x;
    const int w = tid >> 6, l = tid & 63;
    const int lm = l & 15, qd = l >> 4;
    const int m0 = blockIdx.x * 64;

    f32x4 acc[4][3];
#pragma unroll
    for (int r = 0; r < 4; ++r)
#pragma unroll
        for (int t = 0; t < 3; ++t) acc[r][t] = (f32x4){0.f, 0.f, 0.f, 0.f};

    const float* xbase = x + (size_t)(m0 + lm) * E_DIM + qd * 8;

    uint4 wreg[3];
    // stage step 0 W tile
#pragma unroll
    for (int c = 0; c < 3; ++c) {
        int f = (c * 256 + tid) * 8;
        wreg[c] = *(const uint4*)(Wb + ((f >> 5) * E_DIM + (f & 31)));
    }
#pragma unroll
    for (int c = 0; c < 3; ++c)
        *(uint4*)(wlds[0] + (c * 256 + tid) * 8) = wreg[c];

    float4 ar[4][2];
#pragma unroll
    for (int r = 0; r < 4; ++r) {
        const float* p = xbase + (size_t)r * 16 * E_DIM;
        ar[r][0] = *(const float4*)p;
        ar[r][1] = *(const float4*)(p + 4);
    }
    __syncthreads();

    for (int s = 0; s < 32; ++s) {
        const int cb = s & 1, nb = cb ^ 1;
        const bool pre = (s + 1) < 32;
        float4 a2[4][2];
        if (pre) {
            const int k1 = (s + 1) * 32;
#pragma unroll
            for (int c = 0; c < 3; ++c) {
                int f = (c * 256 + tid) * 8;
                wreg[c] = *(const uint4*)(Wb + ((f >> 5) * E_DIM + k1 + (f & 31)));
            }
#pragma unroll
            for (int r = 0; r < 4; ++r) {
                const float* p = xbase + (size_t)r * 16 * E_DIM + k1;
                a2[r][0] = *(const float4*)p;
                a2[r][1] = *(const float4*)(p + 4);
            }
        }
        // convert A fragments (step s)
        bf16x8 af[4];
#pragma unroll
        for (int r = 0; r < 4; ++r) {
            uint4 u;
            u.x = f2bf2(ar[r][0].x, ar[r][0].y);
            u.y = f2bf2(ar[r][0].z, ar[r][0].w);
            u.z = f2bf2(ar[r][1].x, ar[r][1].y);
            u.w = f2bf2(ar[r][1].z, ar[r][1].w);
            af[r] = __builtin_bit_cast(bf16x8, u);
        }
        // B fragments from LDS + MFMA
#pragma unroll
        for (int t = 0; t < 3; ++t) {
            int n = w * 48 + t * 16 + lm;
            uint4 bu = *(const uint4*)(wlds[cb] + n * 32 + qd * 8);
            bf16x8 bf = __builtin_bit_cast(bf16x8, bu);
#pragma unroll
            for (int r = 0; r < 4; ++r)
                acc[r][t] = __builtin_amdgcn_mfma_f32_16x16x32_bf16(af[r], bf, acc[r][t], 0, 0, 0);
        }
        if (pre) {
#pragma unroll
            for (int c = 0; c < 3; ++c)
                *(uint4*)(wlds[nb] + (c * 256 + tid) * 8) = wreg[c];
#pragma unroll
            for (int r = 0; r < 4; ++r) { ar[r][0] = a2[r][0]; ar[r][1] = a2[r][1]; }
        }
        __syncthreads();
    }

    // store
#pragma unroll
    for (int r = 0; r < 4; ++r) {
        int mrow0 = m0 + r * 16 + qd * 4;
#pragma unroll
        for (int t = 0; t < 3; ++t) {
            int gc = w * 48 + t * 16 + lm;
            if (gc < 64) {
#pragma unroll
                for (int rr = 0; rr < 4; ++rr)
                    qb[(size_t)(mrow0 + rr) * 64 + gc] = (ushort)f2bf1(acc[r][t][rr]);
            } else if (gc < 128) {
#pragma unroll
                for (int rr = 0; rr < 4; ++rr)
                    kb[(size_t)(mrow0 + rr) * 64 + (gc - 64)] = (ushort)f2bf1(acc[r][t][rr]);
            } else {
                int bt = mrow0 >> 12;
                int tl = mrow0 & (T_SEQ - 1);
                ushort4 pk;
                pk.x = (ushort)f2bf1(acc[r][t][0]);
                pk.y = (ushort)f2bf1(acc[r][t][1]);
                pk.z = (ushort)f2bf1(acc[r][t][2]);
                pk.w = (ushort)f2bf1(acc[r][t][3]);
                *(ushort4*)(vtb + ((size_t)bt * 64 + (gc - 128)) * T_SEQ + tl) = pk;
            }
        }
    }
}

// ---------------- kernel 2: causal flash attention (no-max softmax) ---------
// one wave per (16 Q rows, key-split h). Partials are additive (no running max).
__global__ __launch_bounds__(64) void flash(const ushort* __restrict__ qb,
                                            const ushort* __restrict__ kb,
                                            const ushort* __restrict__ vtb,
                                            float* __restrict__ Opart,
                                            float* __restrict__ lpart) {
    __shared__ ushort plds[16 * 72];  // +8 pad -> conflict-free b128 reads
    const int l = threadIdx.x;
    const int lm = l & 15, qd = l >> 4;
    const int qi = blockIdx.x;   // Q tile 0..255
    const int bt = blockIdx.y;   // batch
    const int h  = blockIdx.z;   // key split 0/1

    const int r0 = qi * 16;                        // row base within batch
    const size_t rowg = (size_t)bt * T_SEQ + r0;   // global row base

    bf16x8 aq0, aq1;
    {
        const ushort* p = qb + (rowg + lm) * 64 + qd * 8;
        aq0 = __builtin_bit_cast(bf16x8, *(const uint4*)p);
        aq1 = __builtin_bit_cast(bf16x8, *(const uint4*)(p + 32));
    }
    f32x4 o[4];
#pragma unroll
    for (int t = 0; t < 4; ++t) o[t] = (f32x4){0.f, 0.f, 0.f, 0.f};
    float lacc[4] = {0.f, 0.f, 0.f, 0.f};

    const int dkt = qi >> 2;     // diagonal key-tile
    const int nkt = dkt + 1;
    const float SC = 1.0f / 32.0f;  // 1/sqrt(E)

    for (int kt = h; kt < nkt; kt += 2) {
        const size_t kbase = (size_t)bt * T_SEQ + (size_t)kt * 64;
        // S = Q K^T
        f32x4 sfr[4];
#pragma unroll
        for (int t = 0; t < 4; ++t) sfr[t] = (f32x4){0.f, 0.f, 0.f, 0.f};
#pragma unroll
        for (int t = 0; t < 4; ++t) {
            const ushort* kp = kb + (kbase + t * 16 + lm) * 64 + qd * 8;
            bf16x8 b0 = __builtin_bit_cast(bf16x8, *(const uint4*)kp);
            bf16x8 b1 = __builtin_bit_cast(bf16x8, *(const uint4*)(kp + 32));
            sfr[t] = __builtin_amdgcn_mfma_f32_16x16x32_bf16(aq0, b0, sfr[t], 0, 0, 0);
            sfr[t] = __builtin_amdgcn_mfma_f32_16x16x32_bf16(aq1, b1, sfr[t], 0, 0, 0);
        }
        // V fragments (issue loads early to hide latency under softmax VALU)
        uint4 vu[4][2];
#pragma unroll
        for (int t = 0; t < 4; ++t) {
            const ushort* vp = vtb + ((size_t)bt * 64 + t * 16 + lm) * T_SEQ + kt * 64 + qd * 8;
            vu[t][0] = *(const uint4*)vp;
            vu[t][1] = *(const uint4*)(vp + 32);
        }
        // P = exp(S/32) (bounded scores: no max needed), causal mask on diag tile
        const bool diag = (kt == dkt);
#pragma unroll
        for (int t = 0; t < 4; ++t) {
            int c = kt * 64 + t * 16 + lm;  // key col within batch
#pragma unroll
            for (int r = 0; r < 4; ++r) {
                float pe = __expf(sfr[t][r] * SC);
                if (diag && c > (r0 + qd * 4 + r)) pe = 0.f;
                lacc[r] += pe;
                plds[(qd * 4 + r) * 72 + t * 16 + lm] = (ushort)f2bf1(pe);
            }
        }
        __syncthreads();  // C-layout -> A-layout via LDS (single wave: acts as waitcnt)
        bf16x8 ap0, ap1;
        {
            const ushort* pp = plds + lm * 72 + qd * 8;
            ap0 = __builtin_bit_cast(bf16x8, *(const uint4*)pp);
            ap1 = __builtin_bit_cast(bf16x8, *(const uint4*)(pp + 32));
        }
#pragma unroll
        for (int t = 0; t < 4; ++t) {
            bf16x8 v0 = __builtin_bit_cast(bf16x8, vu[t][0]);
            bf16x8 v1 = __builtin_bit_cast(bf16x8, vu[t][1]);
            o[t] = __builtin_amdgcn_mfma_f32_16x16x32_bf16(ap0, v0, o[t], 0, 0, 0);
            o[t] = __builtin_amdgcn_mfma_f32_16x16x32_bf16(ap1, v1, o[t], 0, 0, 0);
        }
        __syncthreads();  // protect plds before next iteration's writes
    }
    // reduce l across the 16-lane row group
#pragma unroll
    for (int r = 0; r < 4; ++r) {
        float v = lacc[r];
        v += __shfl_xor(v, 1);
        v += __shfl_xor(v, 2);
        v += __shfl_xor(v, 4);
        v += __shfl_xor(v, 8);
        lacc[r] = v;
    }
    float* ob = Opart + ((size_t)h * M_TOT + rowg + qd * 4) * 64;
#pragma unroll
    for (int r = 0; r < 4; ++r)
#pragma unroll
        for (int t = 0; t < 4; ++t)
            ob[(size_t)r * 64 + t * 16 + lm] = o[t][r];
    if (lm == 0) {
#pragma unroll
        for (int r = 0; r < 4; ++r)
            lpart[(size_t)h * M_TOT + rowg + qd * 4 + r] = lacc[r];
    }
}

// ---------------- kernel 3: combine split-K partials ------------------------
__global__ __launch_bounds__(256) void combine(const float* __restrict__ Opart,
                                               const float* __restrict__ lpart,
                                               float* __restrict__ out) {
    int i4 = blockIdx.x * 256 + threadIdx.x;  // grid 1024 -> 262144 float4s
    size_t base = (size_t)i4 * 4;
    int row = (int)(base >> 6);
    float lsum = lpart[row] + lpart[M_TOT + row];
    float4 a = *(const float4*)(Opart + base);
    float4 b = *(const float4*)(Opart + (size_t)M_TOT * 64 + base);
    float inv = 1.0f / lsum;
    float4 o;
    o.x = (a.x + b.x) * inv;
    o.y = (a.y + b.y) * inv;
    o.z = (a.z + b.z) * inv;
    o.w = (a.w + b.w) * inv;
    *(float4*)(out + base) = o;
}

extern "C" void kernel_launch(void* const* d_in, const int* in_sizes, int n_in,
                              void* d_out, int out_size, void* d_ws, size_t ws_size,
                              hipStream_t stream) {
    const float* x  = (const float*)d_in[0];
    const float* Wq = (const float*)d_in[1];
    const float* Wk = (const float*)d_in[2];
    const float* Wv = (const float*)d_in[3];
    float* out = (float*)d_out;

    char* ws = (char*)d_ws;
    ushort* Wb  = (ushort*)(ws);                                   // 384 KB
    ushort* qb  = (ushort*)(ws + 393216);                          // 2 MB
    ushort* kb  = (ushort*)(ws + 393216 + 2097152);                // 2 MB
    ushort* vtb = (ushort*)(ws + 393216 + 2 * 2097152);            // 2 MB
    float*  Op  = (float*) (ws + 393216 + 3 * 2097152);            // 16 MB
    float*  lp  = (float*) (ws + 393216 + 3 * 2097152 + 8388608);  // 128 KB

    wcvt<<<96, 256, 0, stream>>>(Wq, Wk, Wv, Wb);
    qkv<<<256, 256, 0, stream>>>(x, Wb, qb, kb, vtb);
    flash<<<dim3(256, 4, 2), 64, 0, stream>>>(qb, kb, vtb, Op, lp);
    combine<<<1024, 256, 0, stream>>>(Op, lp, out);
}

// Round 2
// 243.437 us; speedup vs baseline: 1.0800x; 1.0800x over previous
//
#include <hip/hip_runtime.h>
#include <stdint.h>

typedef __bf16 bf16x8 __attribute__((ext_vector_type(8)));
typedef float  f32x4  __attribute__((ext_vector_type(4)));

#define E_DIM 1024
#define H_DIM 64
#define T_SEQ 4096
#define B_BAT 4
#define M_TOT (B_BAT * T_SEQ)   // 16384

#define AS1(p) ((const __attribute__((address_space(1))) void*)(p))
#define AS3(p) ((__attribute__((address_space(3))) void*)(p))

__device__ __forceinline__ uint32_t f2bf1(float f) {
    uint32_t u = __float_as_uint(f);
    return (u + 0x7FFFu + ((u >> 16) & 1u)) >> 16;
}
__device__ __forceinline__ uint32_t f2bf2(float lo, float hi) {
    return f2bf1(lo) | (f2bf1(hi) << 16);
}

// ---------------- kernel 0: W fp32 -> bf16 (concat [192][1024]); Wq pre-scaled by 1/32
__global__ __launch_bounds__(256) void wcvt(const float* __restrict__ Wq,
                                            const float* __restrict__ Wk,
                                            const float* __restrict__ Wv,
                                            ushort* __restrict__ Wb) {
    int e = (blockIdx.x * 256 + threadIdx.x) * 8;  // grid 96 -> 196608 elems
    const float* src = (e < 65536) ? (Wq + e)
                     : (e < 131072) ? (Wk + (e - 65536))
                     : (Wv + (e - 131072));
    float sc = (e < 65536) ? 0.03125f : 1.0f;  // fold 1/sqrt(E)=1/32 into Wq
    float4 a = *(const float4*)src;
    float4 b = *(const float4*)(src + 4);
    uint4 o;
    o.x = f2bf2(a.x * sc, a.y * sc); o.y = f2bf2(a.z * sc, a.w * sc);
    o.z = f2bf2(b.x * sc, b.y * sc); o.w = f2bf2(b.z * sc, b.w * sc);
    *(uint4*)(Wb + e) = o;
}

// ---------------- kernel 1: QKV projection (bf16 MFMA), 32-row tiles, BK=64 --
// out: qb,kb row-major [16384][64] bf16 ; vtb transposed [B][64][T] bf16
__global__ __launch_bounds__(256, 2) void qkv(const float* __restrict__ x,
                                              const ushort* __restrict__ Wb,
                                              ushort* __restrict__ qb,
                                              ushort* __restrict__ kb,
                                              ushort* __restrict__ vtb) {
    __shared__ ushort wlds[2][192 * 64];  // 24 KB per buffer
    const int tid = threadIdx.x;
    const int w = tid >> 6, l = tid & 63;
    const int lm = l & 15, qd = l >> 4;
    const int m0 = blockIdx.x * 32;

    f32x4 acc[2][3];
#pragma unroll
    for (int r = 0; r < 2; ++r)
#pragma unroll
        for (int t = 0; t < 3; ++t) acc[r][t] = (f32x4){0.f, 0.f, 0.f, 0.f};

    const float* xbase = x + (size_t)(m0 + lm) * E_DIM + qd * 8;

    // stage step-0 W tile [192][64] via async global->LDS (16B/lane)
#pragma unroll
    for (int c = 0; c < 6; ++c) {
        int f = (c * 256 + tid) * 8;
        __builtin_amdgcn_global_load_lds(AS1(Wb + (size_t)(f >> 6) * E_DIM + (f & 63)),
                                         AS3(&wlds[0][f]), 16, 0, 0);
    }
    float4 ar[2][4];
#pragma unroll
    for (int r = 0; r < 2; ++r) {
        const float* p = xbase + (size_t)(r * 16) * E_DIM;
        ar[r][0] = *(const float4*)p;
        ar[r][1] = *(const float4*)(p + 4);
        ar[r][2] = *(const float4*)(p + 32);
        ar[r][3] = *(const float4*)(p + 36);
    }
    __syncthreads();

    for (int s = 0; s < 16; ++s) {
        const int cb = s & 1, nb = cb ^ 1;
        const bool pre = (s + 1) < 16;
        float4 a2[2][4];
        if (pre) {
            const int k1 = (s + 1) * 64;
#pragma unroll
            for (int c = 0; c < 6; ++c) {
                int f = (c * 256 + tid) * 8;
                __builtin_amdgcn_global_load_lds(AS1(Wb + (size_t)(f >> 6) * E_DIM + k1 + (f & 63)),
                                                 AS3(&wlds[nb][f]), 16, 0, 0);
            }
#pragma unroll
            for (int r = 0; r < 2; ++r) {
                const float* p = xbase + (size_t)(r * 16) * E_DIM + k1;
                a2[r][0] = *(const float4*)p;
                a2[r][1] = *(const float4*)(p + 4);
                a2[r][2] = *(const float4*)(p + 32);
                a2[r][3] = *(const float4*)(p + 36);
            }
        }
        // convert A fragments
        bf16x8 af[2][2];
#pragma unroll
        for (int r = 0; r < 2; ++r)
#pragma unroll
            for (int kc = 0; kc < 2; ++kc) {
                float4 f0 = ar[r][kc * 2], f1 = ar[r][kc * 2 + 1];
                uint4 u;
                u.x = f2bf2(f0.x, f0.y); u.y = f2bf2(f0.z, f0.w);
                u.z = f2bf2(f1.x, f1.y); u.w = f2bf2(f1.z, f1.w);
                af[r][kc] = __builtin_bit_cast(bf16x8, u);
            }
        // B from LDS + MFMA
#pragma unroll
        for (int t = 0; t < 3; ++t) {
            int n = w * 48 + t * 16 + lm;
#pragma unroll
            for (int kc = 0; kc < 2; ++kc) {
                uint4 bu = *(const uint4*)(&wlds[cb][n * 64 + kc * 32 + qd * 8]);
                bf16x8 bf = __builtin_bit_cast(bf16x8, bu);
#pragma unroll
                for (int r = 0; r < 2; ++r)
                    acc[r][t] = __builtin_amdgcn_mfma_f32_16x16x32_bf16(af[r][kc], bf, acc[r][t], 0, 0, 0);
            }
        }
        if (pre) {
#pragma unroll
            for (int r = 0; r < 2; ++r)
#pragma unroll
                for (int j = 0; j < 4; ++j) ar[r][j] = a2[r][j];
        }
        __syncthreads();
    }

    // store
#pragma unroll
    for (int r = 0; r < 2; ++r) {
        int mrow0 = m0 + r * 16 + qd * 4;
#pragma unroll
        for (int t = 0; t < 3; ++t) {
            int gc = w * 48 + t * 16 + lm;
            if (gc < 64) {
#pragma unroll
                for (int rr = 0; rr < 4; ++rr)
                    qb[(size_t)(mrow0 + rr) * 64 + gc] = (ushort)f2bf1(acc[r][t][rr]);
            } else if (gc < 128) {
#pragma unroll
                for (int rr = 0; rr < 4; ++rr)
                    kb[(size_t)(mrow0 + rr) * 64 + (gc - 64)] = (ushort)f2bf1(acc[r][t][rr]);
            } else {
                int bt = mrow0 >> 12;
                int tl = mrow0 & (T_SEQ - 1);
                ushort4 pk;
                pk.x = (ushort)f2bf1(acc[r][t][0]);
                pk.y = (ushort)f2bf1(acc[r][t][1]);
                pk.z = (ushort)f2bf1(acc[r][t][2]);
                pk.w = (ushort)f2bf1(acc[r][t][3]);
                *(ushort4*)(vtb + ((size_t)bt * 64 + (gc - 128)) * T_SEQ + tl) = pk;
            }
        }
    }
}

// ---------------- kernel 2: causal flash attention ---------------------------
// block = 4 waves; each wave takes kt = w, w+4, ... (in-block 4-way key split);
// no-max softmax (bounded scores, 1/32 & exp pre-folded into Wq); in-block
// O/l reduction -> direct fp32 output. No barriers in the main loop (per-wave
// private P + HW per-wave LDS ordering).
__global__ __launch_bounds__(256, 4) void flash(const ushort* __restrict__ qb,
                                                const ushort* __restrict__ kb,
                                                const ushort* __restrict__ vtb,
                                                float* __restrict__ out) {
    __shared__ ushort plds[4][16 * 72];   // per-wave P tile (C->A layout hop)
    __shared__ float ored[4][16 * 66];    // per-wave O partial (stride 66: conflict-free)
    __shared__ float lred[4][16];
    const int tid = threadIdx.x;
    const int w = tid >> 6, l = tid & 63;
    const int lm = l & 15, qd = l >> 4;
    const int qi = 255 - (int)blockIdx.x;  // heavy tiles first
    const int bt = blockIdx.y;
    const int r0 = qi * 16;
    const size_t rowg = (size_t)bt * T_SEQ + r0;

    bf16x8 aq0, aq1;
    {
        const ushort* p = qb + (rowg + lm) * 64 + qd * 8;
        aq0 = __builtin_bit_cast(bf16x8, *(const uint4*)p);
        aq1 = __builtin_bit_cast(bf16x8, *(const uint4*)(p + 32));
    }
    f32x4 o[4];
#pragma unroll
    for (int t = 0; t < 4; ++t) o[t] = (f32x4){0.f, 0.f, 0.f, 0.f};
    float lacc[4] = {0.f, 0.f, 0.f, 0.f};

    const int dkt = qi >> 2;
    const int nkt = dkt + 1;
    ushort* myp = plds[w];

    for (int kt = w; kt < nkt; kt += 4) {
        const size_t kbase = (size_t)bt * T_SEQ + (size_t)kt * 64;
        f32x4 sfr[4];
#pragma unroll
        for (int t = 0; t < 4; ++t) sfr[t] = (f32x4){0.f, 0.f, 0.f, 0.f};
#pragma unroll
        for (int t = 0; t < 4; ++t) {
            const ushort* kp = kb + (kbase + t * 16 + lm) * 64 + qd * 8;
            bf16x8 b0 = __builtin_bit_cast(bf16x8, *(const uint4*)kp);
            bf16x8 b1 = __builtin_bit_cast(bf16x8, *(const uint4*)(kp + 32));
            sfr[t] = __builtin_amdgcn_mfma_f32_16x16x32_bf16(aq0, b0, sfr[t], 0, 0, 0);
            sfr[t] = __builtin_amdgcn_mfma_f32_16x16x32_bf16(aq1, b1, sfr[t], 0, 0, 0);
        }
        // V fragment loads issued early
        uint4 vu[4][2];
#pragma unroll
        for (int t = 0; t < 4; ++t) {
            const ushort* vp = vtb + ((size_t)bt * 64 + t * 16 + lm) * T_SEQ + kt * 64 + qd * 8;
            vu[t][0] = *(const uint4*)vp;
            vu[t][1] = *(const uint4*)(vp + 32);
        }
        const bool diag = (kt == dkt);
#pragma unroll
        for (int t = 0; t < 4; ++t) {
            int c = kt * 64 + t * 16 + lm;
#pragma unroll
            for (int r = 0; r < 4; ++r) {
                float pe = __expf(sfr[t][r]);   // scale pre-folded into Wq
                if (diag && c > (r0 + qd * 4 + r)) pe = 0.f;
                lacc[r] += pe;
                myp[(qd * 4 + r) * 72 + t * 16 + lm] = (ushort)f2bf1(pe);
            }
        }
        __builtin_amdgcn_wave_barrier();
        __builtin_amdgcn_s_waitcnt(0xC07F);  // lgkmcnt(0): P writes committed (wave-private tile)
        __builtin_amdgcn_wave_barrier();
        bf16x8 ap0, ap1;
        {
            const ushort* pp = myp + lm * 72 + qd * 8;
            ap0 = __builtin_bit_cast(bf16x8, *(const uint4*)pp);
            ap1 = __builtin_bit_cast(bf16x8, *(const uint4*)(pp + 32));
        }
#pragma unroll
        for (int t = 0; t < 4; ++t) {
            bf16x8 v0 = __builtin_bit_cast(bf16x8, vu[t][0]);
            bf16x8 v1 = __builtin_bit_cast(bf16x8, vu[t][1]);
            o[t] = __builtin_amdgcn_mfma_f32_16x16x32_bf16(ap0, v0, o[t], 0, 0, 0);
            o[t] = __builtin_amdgcn_mfma_f32_16x16x32_bf16(ap1, v1, o[t], 0, 0, 0);
        }
        __builtin_amdgcn_wave_barrier();  // keep next iter's P writes after these reads
    }
    // reduce l across the 16-lane row group
#pragma unroll
    for (int r = 0; r < 4; ++r) {
        float v = lacc[r];
        v += __shfl_xor(v, 1);
        v += __shfl_xor(v, 2);
        v += __shfl_xor(v, 4);
        v += __shfl_xor(v, 8);
        lacc[r] = v;
    }
    // in-block cross-wave reduction
#pragma unroll
    for (int r = 0; r < 4; ++r)
#pragma unroll
        for (int t = 0; t < 4; ++t)
            ored[w][(qd * 4 + r) * 66 + t * 16 + lm] = o[t][r];
    if (lm == 0) {
#pragma unroll
        for (int r = 0; r < 4; ++r) lred[w][qd * 4 + r] = lacc[r];
    }
    __syncthreads();
    const int col = tid & 63, rw = tid >> 6;
#pragma unroll
    for (int rr = 0; rr < 4; ++rr) {
        int row = rr * 4 + rw;
        float s = ored[0][row * 66 + col] + ored[1][row * 66 + col]
                + ored[2][row * 66 + col] + ored[3][row * 66 + col];
        float ls = lred[0][row] + lred[1][row] + lred[2][row] + lred[3][row];
        out[(rowg + row) * 64 + col] = s / ls;
    }
}

extern "C" void kernel_launch(void* const* d_in, const int* in_sizes, int n_in,
                              void* d_out, int out_size, void* d_ws, size_t ws_size,
                              hipStream_t stream) {
    const float* x  = (const float*)d_in[0];
    const float* Wq = (const float*)d_in[1];
    const float* Wk = (const float*)d_in[2];
    const float* Wv = (const float*)d_in[3];
    float* out = (float*)d_out;

    char* ws = (char*)d_ws;
    ushort* Wb  = (ushort*)(ws);                          // 384 KB
    ushort* qb  = (ushort*)(ws + 393216);                 // 2 MB
    ushort* kb  = (ushort*)(ws + 393216 + 2097152);       // 2 MB
    ushort* vtb = (ushort*)(ws + 393216 + 2 * 2097152);   // 2 MB

    wcvt<<<96, 256, 0, stream>>>(Wq, Wk, Wv, Wb);
    qkv<<<512, 256, 0, stream>>>(x, Wb, qb, kb, vtb);
    flash<<<dim3(256, B_BAT), 256, 0, stream>>>(qb, kb, vtb, out);
}

// Round 3
// 141.571 us; speedup vs baseline: 1.8571x; 1.7195x over previous
//
#include <hip/hip_runtime.h>
#include <stdint.h>

typedef __bf16 bf16x8 __attribute__((ext_vector_type(8)));
typedef float  f32x4  __attribute__((ext_vector_type(4)));

#define E_DIM 1024
#define H_DIM 64
#define T_SEQ 4096
#define B_BAT 4
#define M_TOT (B_BAT * T_SEQ)   // 16384

__device__ __forceinline__ uint32_t f2bf1(float f) {
    uint32_t u = __float_as_uint(f);
    return (u + 0x7FFFu + ((u >> 16) & 1u)) >> 16;
}
__device__ __forceinline__ uint32_t f2bf2(float lo, float hi) {
    return f2bf1(lo) | (f2bf1(hi) << 16);
}
__device__ __forceinline__ bf16x8 ldfrag(const ushort* p) {
    return __builtin_bit_cast(bf16x8, *(const uint4*)p);
}

// ---------------- kernel 0: W fp32 -> frag-major bf16 -----------------------
// Wfm[s 16][nt 12][kc 2][lane 64][8]; lane=(qd*16+lm) holds W[n=nt*16+lm][k=s*64+kc*32+qd*8+j]
// Wq rows (n<64) pre-scaled by 1/sqrt(E)=1/32.
__global__ __launch_bounds__(256) void wcvt(const float* __restrict__ Wq,
                                            const float* __restrict__ Wk,
                                            const float* __restrict__ Wv,
                                            ushort* __restrict__ Wfm) {
    int g = blockIdx.x * 256 + threadIdx.x;   // 24576 threads: one 8-elem chunk each
    int n = g >> 7;          // 0..191
    int k8 = g & 127;        // chunk of 8 k
    const float* src = (n < 64) ? (Wq + (size_t)n * E_DIM)
                     : (n < 128) ? (Wk + (size_t)(n - 64) * E_DIM)
                     : (Wv + (size_t)(n - 128) * E_DIM);
    float sc = (n < 64) ? 0.03125f : 1.0f;
    float4 a = *(const float4*)(src + k8 * 8);
    float4 b = *(const float4*)(src + k8 * 8 + 4);
    uint4 o;
    o.x = f2bf2(a.x * sc, a.y * sc); o.y = f2bf2(a.z * sc, a.w * sc);
    o.z = f2bf2(b.x * sc, b.y * sc); o.w = f2bf2(b.z * sc, b.w * sc);
    int s = k8 >> 3, kc = (k8 >> 2) & 1, qd = k8 & 3;
    int nt = n >> 4, lm = n & 15;
    int lane = qd * 16 + lm;
    *(uint4*)(Wfm + (((size_t)(s * 12 + nt) * 2 + kc) * 64 + lane) * 8) = o;
}

// ---------------- kernel 1: QKV projection --------------------------------
// 32-row blocks, BK=64, 16 steps. W frags dense from global (frag-major).
// x staged dense -> LDS(bf16, pad 72) -> frag reads. Epilogue: LDS transpose
// -> frag-major Qfm/Kfm/Vfm dense stores.
__global__ __launch_bounds__(256, 2) void qkv(const float* __restrict__ x,
                                              const ushort* __restrict__ Wfm,
                                              ushort* __restrict__ Qfm,
                                              ushort* __restrict__ Kfm,
                                              ushort* __restrict__ Vfm) {
    __shared__ ushort alds[2][32 * 72];    // bf16 x-tile, pad 72
    __shared__ ushort ldsC[32 * 136];      // [m][n<128] Q|K cols, pad 136
    __shared__ ushort ldsVt[64 * 40];      // [h][m] V transposed, pad 40
    const int tid = threadIdx.x;
    const int w = tid >> 6, l = tid & 63;
    const int lm = l & 15, qd = l >> 4;
    const int m0 = blockIdx.x * 32;

    f32x4 acc[2][3];
#pragma unroll
    for (int r2 = 0; r2 < 2; ++r2)
#pragma unroll
        for (int t = 0; t < 3; ++t) acc[r2][t] = (f32x4){0.f, 0.f, 0.f, 0.f};

    // x staging: thread covers row=tid>>3, kseg=tid&7 (8 bf16 per step)
    const int srow = tid >> 3, kseg = tid & 7;
    const float* xsrc = x + (size_t)(m0 + srow) * E_DIM + kseg * 8;

    {   // stage step 0
        float4 a0 = *(const float4*)xsrc;
        float4 a1 = *(const float4*)(xsrc + 4);
        uint4 u;
        u.x = f2bf2(a0.x, a0.y); u.y = f2bf2(a0.z, a0.w);
        u.z = f2bf2(a1.x, a1.y); u.w = f2bf2(a1.z, a1.w);
        *(uint4*)(&alds[0][srow * 72 + kseg * 8]) = u;
    }
    __syncthreads();

    for (int s = 0; s < 16; ++s) {
        const int cb = s & 1, nb = cb ^ 1;
        const bool pre = s < 15;
        float4 n0, n1;
        if (pre) {
            n0 = *(const float4*)(xsrc + (s + 1) * 64);
            n1 = *(const float4*)(xsrc + (s + 1) * 64 + 4);
        }
        // W frags: dense global (L2-resident)
        bf16x8 wf[3][2];
#pragma unroll
        for (int t = 0; t < 3; ++t)
#pragma unroll
            for (int kc = 0; kc < 2; ++kc)
                wf[t][kc] = ldfrag(Wfm + (((size_t)(s * 12 + w * 3 + t) * 2 + kc) * 64 + l) * 8);
        // A frags from LDS
        bf16x8 af[2][2];
#pragma unroll
        for (int r2 = 0; r2 < 2; ++r2)
#pragma unroll
            for (int kc = 0; kc < 2; ++kc)
                af[r2][kc] = ldfrag(&alds[cb][(r2 * 16 + lm) * 72 + kc * 32 + qd * 8]);
#pragma unroll
        for (int t = 0; t < 3; ++t)
#pragma unroll
            for (int kc = 0; kc < 2; ++kc)
#pragma unroll
                for (int r2 = 0; r2 < 2; ++r2)
                    acc[r2][t] = __builtin_amdgcn_mfma_f32_16x16x32_bf16(af[r2][kc], wf[t][kc], acc[r2][t], 0, 0, 0);
        if (pre) {
            uint4 u;
            u.x = f2bf2(n0.x, n0.y); u.y = f2bf2(n0.z, n0.w);
            u.z = f2bf2(n1.x, n1.y); u.w = f2bf2(n1.z, n1.w);
            *(uint4*)(&alds[nb][srow * 72 + kseg * 8]) = u;
        }
        __syncthreads();
    }

    // epilogue: acc -> LDS (transpose) -> frag-major dense stores
#pragma unroll
    for (int r2 = 0; r2 < 2; ++r2)
#pragma unroll
        for (int t = 0; t < 3; ++t) {
            int gc = w * 48 + t * 16 + lm;
            int m = r2 * 16 + qd * 4;
#pragma unroll
            for (int rr = 0; rr < 4; ++rr) {
                ushort v = (ushort)f2bf1(acc[r2][t][rr]);
                if (gc < 128) ldsC[(m + rr) * 136 + gc] = v;
                else          ldsVt[(gc - 128) * 40 + (m + rr)] = v;
            }
        }
    __syncthreads();

    const int g16b = m0 >> 4;            // Q 16-row tile base
    const int kt64 = m0 >> 6;            // K/V 64-key tile
    const int tb   = (m0 >> 4) & 3;      // 0 or 2: K t-group base
    const int kcv  = (m0 >> 5) & 1;      // V kc half
#pragma unroll
    for (int ii = 0; ii < 3; ++ii) {
        int i = w + ii * 4;              // 12 chunks, 3 per wave
        uint4 val;
        ushort* dst;
        if (i < 4) {
            int qt_l = i >> 1, kc = i & 1;
            val = *(const uint4*)(&ldsC[(qt_l * 16 + lm) * 136 + kc * 32 + qd * 8]);
            dst = Qfm + (((size_t)(g16b + qt_l) * 2 + kc) * 64 + l) * 8;
        } else if (i < 8) {
            int j2 = i - 4, t_l = j2 >> 1, kc = j2 & 1;
            val = *(const uint4*)(&ldsC[(t_l * 16 + lm) * 136 + 64 + kc * 32 + qd * 8]);
            dst = Kfm + (((size_t)((kt64 * 4 + tb + t_l) * 2 + kc)) * 64 + l) * 8;
        } else {
            int t = i - 8;
            val = *(const uint4*)(&ldsVt[(t * 16 + lm) * 40 + qd * 8]);
            dst = Vfm + (((size_t)((kt64 * 4 + t) * 2 + kcv)) * 64 + l) * 8;
        }
        *(uint4*)dst = val;
    }
}

// ---------------- kernel 2: causal flash attention --------------------------
// S^T = K·Q^T (operand swap -> both frags dense). Pair-balanced tiles
// (p, 63-p), split-4 keys across blocks. 4 waves, each owns 16 Q rows.
// No in-loop barriers (wave-private P LDS).
__global__ __launch_bounds__(256, 2) void flash(const ushort* __restrict__ Qfm,
                                                const ushort* __restrict__ Kfm,
                                                const ushort* __restrict__ Vfm,
                                                float* __restrict__ Opart,
                                                float* __restrict__ lpart) {
    __shared__ ushort plds[4][16 * 80];  // per-wave P tile [qrow][key], pad 80
    const int tid = threadIdx.x;
    const int wv = tid >> 6, l = tid & 63;
    const int lm = l & 15, qd = l >> 4;
    const int pr = blockIdx.x;   // pair 0..31
    const int bt = blockIdx.y;   // batch
    const int h  = blockIdx.z;   // key split 0..3
    ushort* myp = plds[wv];

#pragma unroll 1
    for (int half = 0; half < 2; ++half) {
        const int qt = half ? (63 - pr) : pr;           // 64-row Q tile
        const int qrow = qt * 64 + wv * 16 + lm;        // this lane's Q row (in batch)
        const size_t rowg = (size_t)bt * T_SEQ + qt * 64 + wv * 16;
        const int g16 = bt * 256 + qt * 4 + wv;

        bf16x8 qf0, qf1;
        {
            const ushort* qp = Qfm + ((size_t)g16 * 2) * 512 + l * 8;
            qf0 = ldfrag(qp);
            qf1 = ldfrag(qp + 512);
        }
        f32x4 o[4];
#pragma unroll
        for (int t = 0; t < 4; ++t) o[t] = (f32x4){0.f, 0.f, 0.f, 0.f};
        float lacc = 0.f;

#pragma unroll 1
        for (int kt = h; kt <= qt; kt += 4) {
            const ushort* kb = Kfm + ((size_t)(bt * 64 + kt) * 8) * 512;
            const ushort* vb = Vfm + ((size_t)(bt * 64 + kt) * 8) * 512;
            // S^T = K·Q^T  (A=K frag, B=Q frag; all dense 1KB loads)
            f32x4 sf[4];
#pragma unroll
            for (int t = 0; t < 4; ++t) sf[t] = (f32x4){0.f, 0.f, 0.f, 0.f};
#pragma unroll
            for (int t = 0; t < 4; ++t) {
                bf16x8 k0 = ldfrag(kb + (t * 2 + 0) * 512 + l * 8);
                bf16x8 k1 = ldfrag(kb + (t * 2 + 1) * 512 + l * 8);
                sf[t] = __builtin_amdgcn_mfma_f32_16x16x32_bf16(k0, qf0, sf[t], 0, 0, 0);
                sf[t] = __builtin_amdgcn_mfma_f32_16x16x32_bf16(k1, qf1, sf[t], 0, 0, 0);
            }
            // V frags issued early (hide under exp)
            uint4 vu[4][2];
#pragma unroll
            for (int t = 0; t < 4; ++t) {
                vu[t][0] = *(const uint4*)(vb + (t * 2 + 0) * 512 + l * 8);
                vu[t][1] = *(const uint4*)(vb + (t * 2 + 1) * 512 + l * 8);
            }
            // P = exp(S) (scale folded into Wq), causal mask, write P tile
#pragma unroll
            for (int t = 0; t < 4; ++t) {
                int keyb = kt * 64 + t * 16 + qd * 4;
#pragma unroll
                for (int rr = 0; rr < 4; ++rr) {
                    float pe = __expf(sf[t][rr]);
                    if (keyb + rr > qrow) pe = 0.f;
                    lacc += pe;
                    myp[lm * 80 + t * 16 + qd * 4 + rr] = (ushort)f2bf1(pe);
                }
            }
            __builtin_amdgcn_wave_barrier();
            __builtin_amdgcn_s_waitcnt(0xC07F);  // lgkmcnt(0)
            __builtin_amdgcn_wave_barrier();
            bf16x8 pf0 = ldfrag(myp + lm * 80 + qd * 8);
            bf16x8 pf1 = ldfrag(myp + lm * 80 + 32 + qd * 8);
#pragma unroll
            for (int t = 0; t < 4; ++t) {
                bf16x8 v0 = __builtin_bit_cast(bf16x8, vu[t][0]);
                bf16x8 v1 = __builtin_bit_cast(bf16x8, vu[t][1]);
                o[t] = __builtin_amdgcn_mfma_f32_16x16x32_bf16(pf0, v0, o[t], 0, 0, 0);
                o[t] = __builtin_amdgcn_mfma_f32_16x16x32_bf16(pf1, v1, o[t], 0, 0, 0);
            }
            __builtin_amdgcn_wave_barrier();
        }
        // l: sum over the 4 qd groups (same qrow lives in lanes lm, lm+16, lm+32, lm+48)
        lacc += __shfl_xor(lacc, 16);
        lacc += __shfl_xor(lacc, 32);

        float* ob = Opart + ((size_t)h * M_TOT + rowg) * 64;
#pragma unroll
        for (int t = 0; t < 4; ++t)
#pragma unroll
            for (int rr = 0; rr < 4; ++rr)
                ob[(size_t)(qd * 4 + rr) * 64 + t * 16 + lm] = o[t][rr];
        if (qd == 0) lpart[(size_t)h * M_TOT + rowg + lm] = lacc;
    }
}

// ---------------- kernel 3: combine split-4 partials ------------------------
__global__ __launch_bounds__(256) void combine(const float* __restrict__ Opart,
                                               const float* __restrict__ lpart,
                                               float* __restrict__ out) {
    int i4 = blockIdx.x * 256 + threadIdx.x;   // 262144 float4s
    size_t base = (size_t)i4 * 4;
    int row = i4 >> 4;
    float ls = lpart[row] + lpart[M_TOT + row] + lpart[2 * M_TOT + row] + lpart[3 * M_TOT + row];
    const size_t SP = (size_t)M_TOT * 64;
    float4 a = *(const float4*)(Opart + base);
    float4 b = *(const float4*)(Opart + SP + base);
    float4 c = *(const float4*)(Opart + 2 * SP + base);
    float4 d = *(const float4*)(Opart + 3 * SP + base);
    float inv = 1.0f / ls;
    float4 o;
    o.x = (a.x + b.x + c.x + d.x) * inv;
    o.y = (a.y + b.y + c.y + d.y) * inv;
    o.z = (a.z + b.z + c.z + d.z) * inv;
    o.w = (a.w + b.w + c.w + d.w) * inv;
    *(float4*)(out + base) = o;
}

extern "C" void kernel_launch(void* const* d_in, const int* in_sizes, int n_in,
                              void* d_out, int out_size, void* d_ws, size_t ws_size,
                              hipStream_t stream) {
    const float* x  = (const float*)d_in[0];
    const float* Wq = (const float*)d_in[1];
    const float* Wk = (const float*)d_in[2];
    const float* Wv = (const float*)d_in[3];
    float* out = (float*)d_out;

    char* ws = (char*)d_ws;
    ushort* Wfm = (ushort*)(ws);                 // 384 KB
    ushort* Qfm = (ushort*)(ws + 393216);        // 2 MB
    ushort* Kfm = (ushort*)(ws + 2490368);       // 2 MB
    ushort* Vfm = (ushort*)(ws + 4587520);       // 2 MB
    float*  Op  = (float*) (ws + 6684672);       // 16 MB
    float*  lp  = (float*) (ws + 23461888);      // 256 KB

    wcvt<<<96, 256, 0, stream>>>(Wq, Wk, Wv, Wfm);
    qkv<<<512, 256, 0, stream>>>(x, Wfm, Qfm, Kfm, Vfm);
    flash<<<dim3(32, B_BAT, 4), 256, 0, stream>>>(Qfm, Kfm, Vfm, Op, lp);
    combine<<<1024, 256, 0, stream>>>(Op, lp, out);
}

// Round 5
// 135.844 us; speedup vs baseline: 1.9354x; 1.0422x over previous
//
#include <hip/hip_runtime.h>
#include <stdint.h>

typedef __bf16 bf16x8 __attribute__((ext_vector_type(8)));
typedef float  f32x4  __attribute__((ext_vector_type(4)));

#define E_DIM 1024
#define H_DIM 64
#define T_SEQ 4096
#define B_BAT 4
#define M_TOT (B_BAT * T_SEQ)   // 16384

__device__ __forceinline__ uint32_t f2bf1(float f) {
    uint32_t u = __float_as_uint(f);
    return (u + 0x7FFFu + ((u >> 16) & 1u)) >> 16;
}
// packed fp32x2 -> bf16x2 (RNE)
__device__ __forceinline__ uint32_t pk2(float lo, float hi) {
    return f2bf1(lo) | (f2bf1(hi) << 16);
}
__device__ __forceinline__ bf16x8 ldfrag(const ushort* p) {
    return __builtin_bit_cast(bf16x8, *(const uint4*)(p));
}
// barrier that waits LDS only — global prefetch stays in flight (vmcnt not drained)
__device__ __forceinline__ void barrier_lgkm() {
    __builtin_amdgcn_s_waitcnt(0xC07F);   // vmcnt(63) expcnt(7) lgkmcnt(0)
    __builtin_amdgcn_s_barrier();
}

// ---------------- kernel 0: W fp32 -> frag-major bf16 -----------------------
// Wfm[s 16][nt 12][kc 2][lane 64][8]; Wq rows (n<64) pre-scaled by 1/32.
__global__ __launch_bounds__(256) void wcvt(const float* __restrict__ Wq,
                                            const float* __restrict__ Wk,
                                            const float* __restrict__ Wv,
                                            ushort* __restrict__ Wfm) {
    int g = blockIdx.x * 256 + threadIdx.x;   // 24576 threads
    int n = g >> 7;          // 0..191
    int k8 = g & 127;
    const float* src = (n < 64) ? (Wq + (size_t)n * E_DIM)
                     : (n < 128) ? (Wk + (size_t)(n - 64) * E_DIM)
                     : (Wv + (size_t)(n - 128) * E_DIM);
    float sc = (n < 64) ? 0.03125f : 1.0f;
    float4 a = *(const float4*)(src + k8 * 8);
    float4 b = *(const float4*)(src + k8 * 8 + 4);
    uint4 o;
    o.x = pk2(a.x * sc, a.y * sc); o.y = pk2(a.z * sc, a.w * sc);
    o.z = pk2(b.x * sc, b.y * sc); o.w = pk2(b.z * sc, b.w * sc);
    int s = k8 >> 3, kc = (k8 >> 2) & 1, qd = k8 & 3;
    int nt = n >> 4, lm = n & 15;
    int lane = qd * 16 + lm;
    *(uint4*)(Wfm + (((size_t)(s * 12 + nt) * 2 + kc) * 64 + lane) * 8) = o;
}

// ---------------- kernel 1: QKV projection ----------------------------------
// 32-row blocks, BK=64, 16 steps. 2-deep x pipeline (load s+2 / stage s+1 /
// compute s); lgkm-only in-loop barriers keep global loads in flight.
__global__ __launch_bounds__(256, 3) void qkv(const float* __restrict__ x,
                                              const ushort* __restrict__ Wfm,
                                              ushort* __restrict__ Qfm,
                                              ushort* __restrict__ Kfm,
                                              ushort* __restrict__ Vfm) {
    __shared__ union {
        ushort a[2][32 * 72];                              // staging dbuf (9216 B)
        struct { ushort c[32 * 136]; ushort vt[64 * 40]; } epi;  // epilogue (13824 B)
    } sm;
    const int tid = threadIdx.x;
    const int w = tid >> 6, l = tid & 63;
    const int lm = l & 15, qd = l >> 4;
    const int m0 = blockIdx.x * 32;

    f32x4 acc[2][3];
#pragma unroll
    for (int r2 = 0; r2 < 2; ++r2)
#pragma unroll
        for (int t = 0; t < 3; ++t) acc[r2][t] = (f32x4){0.f, 0.f, 0.f, 0.f};

    const int srow = tid >> 3, kseg = tid & 7;
    const float* xsrc = x + (size_t)(m0 + srow) * E_DIM + kseg * 8;

    // tile 0 -> LDS[0]
    {
        float4 a0 = *(const float4*)xsrc;
        float4 a1 = *(const float4*)(xsrc + 4);
        uint4 u = {pk2(a0.x, a0.y), pk2(a0.z, a0.w), pk2(a1.x, a1.y), pk2(a1.z, a1.w)};
        *(uint4*)(&sm.a[0][srow * 72 + kseg * 8]) = u;
    }
    // tile 1 -> regs
    float4 xn0 = *(const float4*)(xsrc + 64);
    float4 xn1 = *(const float4*)(xsrc + 68);
    __syncthreads();

    for (int s = 0; s < 16; ++s) {
        const int cb = s & 1, nb = cb ^ 1;
        float4 x20 = xn0, x21 = xn1;
        if (s < 14) {                       // load tile s+2
            x20 = *(const float4*)(xsrc + (s + 2) * 64);
            x21 = *(const float4*)(xsrc + (s + 2) * 64 + 4);
        }
        // W frags for this step (global, L2-resident, lane-dense)
        bf16x8 wf[3][2];
#pragma unroll
        for (int t = 0; t < 3; ++t)
#pragma unroll
            for (int kc = 0; kc < 2; ++kc)
                wf[t][kc] = ldfrag(Wfm + (((size_t)(s * 12 + w * 3 + t) * 2 + kc) * 64 + l) * 8);
        // A frags from LDS
        bf16x8 af[2][2];
#pragma unroll
        for (int r2 = 0; r2 < 2; ++r2)
#pragma unroll
            for (int kc = 0; kc < 2; ++kc)
                af[r2][kc] = ldfrag(&sm.a[cb][(r2 * 16 + lm) * 72 + kc * 32 + qd * 8]);
#pragma unroll
        for (int t = 0; t < 3; ++t)
#pragma unroll
            for (int kc = 0; kc < 2; ++kc)
#pragma unroll
                for (int r2 = 0; r2 < 2; ++r2)
                    acc[r2][t] = __builtin_amdgcn_mfma_f32_16x16x32_bf16(af[r2][kc], wf[t][kc], acc[r2][t], 0, 0, 0);
        // stage tile s+1 (regs loaded one full step ago)
        if (s < 15) {
            uint4 u = {pk2(xn0.x, xn0.y), pk2(xn0.z, xn0.w), pk2(xn1.x, xn1.y), pk2(xn1.z, xn1.w)};
            *(uint4*)(&sm.a[nb][srow * 72 + kseg * 8]) = u;
        }
        xn0 = x20; xn1 = x21;
        if (s < 15) barrier_lgkm();
    }
    __syncthreads();

    // epilogue: acc -> LDS transpose -> frag-major dense stores
#pragma unroll
    for (int r2 = 0; r2 < 2; ++r2)
#pragma unroll
        for (int t = 0; t < 3; ++t) {
            int gc = w * 48 + t * 16 + lm;
            int m = r2 * 16 + qd * 4;
#pragma unroll
            for (int rr = 0; rr < 4; ++rr) {
                ushort v = (ushort)f2bf1(acc[r2][t][rr]);
                if (gc < 128) sm.epi.c[(m + rr) * 136 + gc] = v;
                else          sm.epi.vt[(gc - 128) * 40 + (m + rr)] = v;
            }
        }
    __syncthreads();

    const int g16b = m0 >> 4;
    const int kt64 = m0 >> 6;
    const int tb   = (m0 >> 4) & 3;
    const int kcv  = (m0 >> 5) & 1;
#pragma unroll
    for (int ii = 0; ii < 3; ++ii) {
        int i = w + ii * 4;
        uint4 val;
        ushort* dst;
        if (i < 4) {
            int qt_l = i >> 1, kc = i & 1;
            val = *(const uint4*)(&sm.epi.c[(qt_l * 16 + lm) * 136 + kc * 32 + qd * 8]);
            dst = Qfm + (((size_t)(g16b + qt_l) * 2 + kc) * 64 + l) * 8;
        } else if (i < 8) {
            int j2 = i - 4, t_l = j2 >> 1, kc = j2 & 1;
            val = *(const uint4*)(&sm.epi.c[(t_l * 16 + lm) * 136 + 64 + kc * 32 + qd * 8]);
            dst = Kfm + (((size_t)((kt64 * 4 + tb + t_l) * 2 + kc)) * 64 + l) * 8;
        } else {
            int t = i - 8;
            val = *(const uint4*)(&sm.epi.vt[(t * 16 + lm) * 40 + qd * 8]);
            dst = Vfm + (((size_t)((kt64 * 4 + t) * 2 + kcv)) * 64 + l) * 8;
        }
        *(uint4*)dst = val;
    }
}

// ---------------- kernel 2: causal flash attention --------------------------
// S^T = K·Q^T; pair-balanced (p, 63-p); split-4 keys across blocks; mask only
// the diagonal tile; packed b64 P writes; wave-private P LDS (no block barriers).
__global__ __launch_bounds__(256, 4) void flash(const ushort* __restrict__ Qfm,
                                                const ushort* __restrict__ Kfm,
                                                const ushort* __restrict__ Vfm,
                                                float* __restrict__ Opart,
                                                float* __restrict__ lpart) {
    __shared__ ushort plds[4][16 * 72];  // stride 72: odd 16B-slot stride -> bank-uniform
    const int tid = threadIdx.x;
    const int wv = tid >> 6, l = tid & 63;
    const int lm = l & 15, qd = l >> 4;
    const int pr = blockIdx.x;   // pair 0..31
    const int bt = blockIdx.y;
    const int h  = blockIdx.z;   // key split 0..3
    ushort* myp = plds[wv];

#pragma unroll 1
    for (int half = 0; half < 2; ++half) {
        const int qt = half ? (63 - pr) : pr;
        const size_t rowg = (size_t)bt * T_SEQ + qt * 64 + wv * 16;
        const int g16 = bt * 256 + qt * 4 + wv;

        bf16x8 qf0, qf1;
        {
            const ushort* qp = Qfm + ((size_t)g16 * 2) * 512 + l * 8;
            qf0 = ldfrag(qp);
            qf1 = ldfrag(qp + 512);
        }
        f32x4 o[4];
#pragma unroll
        for (int t = 0; t < 4; ++t) o[t] = (f32x4){0.f, 0.f, 0.f, 0.f};
        float lacc = 0.f;

#pragma unroll 1
        for (int kt = h; kt <= qt; kt += 4) {
            const ushort* kb = Kfm + ((size_t)(bt * 64 + kt) * 8) * 512;
            const ushort* vb = Vfm + ((size_t)(bt * 64 + kt) * 8) * 512;
            f32x4 sf[4];
#pragma unroll
            for (int t = 0; t < 4; ++t) sf[t] = (f32x4){0.f, 0.f, 0.f, 0.f};
#pragma unroll
            for (int t = 0; t < 4; ++t) {
                bf16x8 k0 = ldfrag(kb + (t * 2 + 0) * 512 + l * 8);
                bf16x8 k1 = ldfrag(kb + (t * 2 + 1) * 512 + l * 8);
                sf[t] = __builtin_amdgcn_mfma_f32_16x16x32_bf16(k0, qf0, sf[t], 0, 0, 0);
                sf[t] = __builtin_amdgcn_mfma_f32_16x16x32_bf16(k1, qf1, sf[t], 0, 0, 0);
            }
            uint4 vu[4][2];
#pragma unroll
            for (int t = 0; t < 4; ++t) {
                vu[t][0] = *(const uint4*)(vb + (t * 2 + 0) * 512 + l * 8);
                vu[t][1] = *(const uint4*)(vb + (t * 2 + 1) * 512 + l * 8);
            }
            ushort* wp = myp + lm * 72 + qd * 4;
            if (kt != qt) {            // fully unmasked tile
#pragma unroll
                for (int t = 0; t < 4; ++t) {
                    float p0 = __expf(sf[t][0]), p1 = __expf(sf[t][1]);
                    float p2 = __expf(sf[t][2]), p3 = __expf(sf[t][3]);
                    lacc += (p0 + p1) + (p2 + p3);
                    *(uint2*)(wp + t * 16) = uint2{pk2(p0, p1), pk2(p2, p3)};
                }
            } else {                   // diagonal tile: t<wv full, t==wv tri, t>wv zero
#pragma unroll
                for (int t = 0; t < 4; ++t) {
                    if (t < wv) {
                        float p0 = __expf(sf[t][0]), p1 = __expf(sf[t][1]);
                        float p2 = __expf(sf[t][2]), p3 = __expf(sf[t][3]);
                        lacc += (p0 + p1) + (p2 + p3);
                        *(uint2*)(wp + t * 16) = uint2{pk2(p0, p1), pk2(p2, p3)};
                    } else if (t == wv) {
                        float p[4];
#pragma unroll
                        for (int rr = 0; rr < 4; ++rr) {
                            float pe = __expf(sf[t][rr]);
                            if (qd * 4 + rr > lm) pe = 0.f;
                            lacc += pe;
                            p[rr] = pe;
                        }
                        *(uint2*)(wp + t * 16) = uint2{pk2(p[0], p[1]), pk2(p[2], p[3])};
                    } else {
                        *(uint2*)(wp + t * 16) = uint2{0u, 0u};
                    }
                }
            }
            __builtin_amdgcn_wave_barrier();
            __builtin_amdgcn_s_waitcnt(0xC07F);  // lgkmcnt(0): P committed (wave-private)
            __builtin_amdgcn_wave_barrier();
            bf16x8 pf0 = ldfrag(myp + lm * 72 + qd * 8);
            bf16x8 pf1 = ldfrag(myp + lm * 72 + 32 + qd * 8);
#pragma unroll
            for (int t = 0; t < 4; ++t) {
                bf16x8 v0 = __builtin_bit_cast(bf16x8, vu[t][0]);
                bf16x8 v1 = __builtin_bit_cast(bf16x8, vu[t][1]);
                o[t] = __builtin_amdgcn_mfma_f32_16x16x32_bf16(pf0, v0, o[t], 0, 0, 0);
                o[t] = __builtin_amdgcn_mfma_f32_16x16x32_bf16(pf1, v1, o[t], 0, 0, 0);
            }
            __builtin_amdgcn_wave_barrier();  // next iter's P writes stay after these reads
        }
        lacc += __shfl_xor(lacc, 16);
        lacc += __shfl_xor(lacc, 32);

        float* ob = Opart + ((size_t)h * M_TOT + rowg) * 64;
#pragma unroll
        for (int t = 0; t < 4; ++t)
#pragma unroll
            for (int rr = 0; rr < 4; ++rr)
                ob[(size_t)(qd * 4 + rr) * 64 + t * 16 + lm] = o[t][rr];
        if (qd == 0) lpart[(size_t)h * M_TOT + rowg + lm] = lacc;
    }
}

// ---------------- kernel 3: combine split-4 partials ------------------------
__global__ __launch_bounds__(256) void combine(const float* __restrict__ Opart,
                                               const float* __restrict__ lpart,
                                               float* __restrict__ out) {
    int i4 = blockIdx.x * 256 + threadIdx.x;   // 262144 float4s
    size_t base = (size_t)i4 * 4;
    int row = i4 >> 4;
    float ls = lpart[row] + lpart[M_TOT + row] + lpart[2 * M_TOT + row] + lpart[3 * M_TOT + row];
    const size_t SP = (size_t)M_TOT * 64;
    float4 a = *(const float4*)(Opart + base);
    float4 b = *(const float4*)(Opart + SP + base);
    float4 c = *(const float4*)(Opart + 2 * SP + base);
    float4 d = *(const float4*)(Opart + 3 * SP + base);
    float inv = 1.0f / ls;
    float4 o;
    o.x = (a.x + b.x + c.x + d.x) * inv;
    o.y = (a.y + b.y + c.y + d.y) * inv;
    o.z = (a.z + b.z + c.z + d.z) * inv;
    o.w = (a.w + b.w + c.w + d.w) * inv;
    *(float4*)(out + base) = o;
}

extern "C" void kernel_launch(void* const* d_in, const int* in_sizes, int n_in,
                              void* d_out, int out_size, void* d_ws, size_t ws_size,
                              hipStream_t stream) {
    const float* x  = (const float*)d_in[0];
    const float* Wq = (const float*)d_in[1];
    const float* Wk = (const float*)d_in[2];
    const float* Wv = (const float*)d_in[3];
    float* out = (float*)d_out;

    char* ws = (char*)d_ws;
    ushort* Wfm = (ushort*)(ws);                 // 384 KB
    ushort* Qfm = (ushort*)(ws + 393216);        // 2 MB
    ushort* Kfm = (ushort*)(ws + 2490368);       // 2 MB
    ushort* Vfm = (ushort*)(ws + 4587520);       // 2 MB
    float*  Op  = (float*) (ws + 6684672);       // 16 MB
    float*  lp  = (float*) (ws + 23461888);      // 256 KB

    wcvt<<<96, 256, 0, stream>>>(Wq, Wk, Wv, Wfm);
    qkv<<<512, 256, 0, stream>>>(x, Wfm, Qfm, Kfm, Vfm);
    flash<<<dim3(32, B_BAT, 4), 256, 0, stream>>>(Qfm, Kfm, Vfm, Op, lp);
    combine<<<1024, 256, 0, stream>>>(Op, lp, out);
}